// Round 9
// baseline (794.854 us; speedup 1.0000x reference)
//
#include <hip/hip_runtime.h>

// 2-layer LSTM (H=64, D=1), N=2048, T=512 — MFMA bf16 3-term split precision.
// R9: BARRIER-FREE producer-consumer. R6's E/O wave split (128 blocks x 512
// threads; E waves 0-3 = L1, O waves 4-7 = L2+out) but lockstep __syncthreads
// replaced by LDS flag sync:
//   - h1/h2 planes quad-buffered by step (slot = k & 3)
//   - cntE[w] / cntO[w]: last completed step per wave (init -1)
//   - E(k) waits min(cntE) >= k-1 && min(cntO) >= k-4   (slot-reuse safety)
//   - O(j) waits min(cntE) >= j   && min(cntO) >= j-1
//   - signal: s_waitcnt lgkmcnt(0) then lane0 flag write
// Invariants (checked): role spread <=1, O in [E-4, E], every overwritten
// slot's readers complete, no circular wait -> deadlock-free.
// MFMA chains split into 2 accumulators (halved dependency depth).

typedef __attribute__((ext_vector_type(8))) short short8;
typedef __attribute__((ext_vector_type(4))) float f32x4;

#define NT 512
#define XPITCH 2060              // 515 words (odd) -> conflict-free x reads
#define XP 0                     // 16 * 2060 = 32960
#define HP 32960                 // 16 planes * 2304 = 36864
#define RING 69824               // 128 slots * 256 B (4 ow x 16 s x f32)
#define FLG 102592               // cntE[4] @ +0, cntO[4] @ +16
#define LDS_BYTES 102720
// plane(layer 0=h1/1=h2, slot 0..3, hl): [16 s][144 B], row j at byte s*144+2j
#define PLANE(layer, slot, hl) (HP + ((((layer) * 4 + (slot)) * 2) + (hl)) * 2304)

__device__ __forceinline__ float fast_rcp(float x) { return __builtin_amdgcn_rcpf(x); }
__device__ __forceinline__ unsigned short bf_rne(float f) {
  unsigned u = __float_as_uint(f);
  return (unsigned short)((u + 0x7FFFu + ((u >> 16) & 1u)) >> 16);
}
__device__ __forceinline__ void split8(const float* p, short8& hi, short8& lo) {
#pragma unroll
  for (int e = 0; e < 8; ++e) {
    float v = p[e];
    unsigned short h = bf_rne(v);
    float hf = __uint_as_float(((unsigned)h) << 16);
    hi[e] = (short)h;
    lo[e] = (short)bf_rne(v - hf);
  }
}
__device__ __forceinline__ unsigned cvt_pk(float a, float b) {
  unsigned r;
  asm("v_cvt_pk_bf16_f32 %0, %1, %2" : "=v"(r) : "v"(a), "v"(b));
  return r;
}
__device__ __forceinline__ f32x4 mfma16(short8 a, short8 b, f32x4 c) {
  return __builtin_amdgcn_mfma_f32_16x16x32_bf16(a, b, c, 0, 0, 0);
}
// (c,h) update from 4 gate pre-activations: 5 exp + 3 rcp.
__device__ __forceinline__ void cell(float i, float f, float gg, float o,
                                     float& c, float& h) {
  const float ei = __expf(-i), ef = __expf(-f), eg = __expf(-2.f * gg),
              eo = __expf(-o);
  const float P = (1.f - eg) * fast_rcp((1.f + ei) * (1.f + eg));
  c = fmaf(c, fast_rcp(1.f + ef), P);
  const float cc = fminf(15.f, fmaxf(-15.f, c));
  const float ec = __expf(-2.f * cc);
  h = (1.f - ec) * fast_rcp((1.f + eo) * (1.f + ec));
}
__device__ __forceinline__ void wait_min_ge(const volatile int* c4, int need) {
  while (true) {
    const int m = min(min(c4[0], c4[1]), min(c4[2], c4[3]));
    if (m >= need) return;
    __builtin_amdgcn_s_sleep(1);
  }
}

__global__ __launch_bounds__(512, 2) void lstm2_async(
    const float* __restrict__ y, const float* __restrict__ Wih1,
    const float* __restrict__ Whh1, const float* __restrict__ bih1,
    const float* __restrict__ bhh1, const float* __restrict__ Wih2,
    const float* __restrict__ Whh2, const float* __restrict__ bih2,
    const float* __restrict__ bhh2, const float* __restrict__ Wlin,
    const float* __restrict__ blin, float* __restrict__ out) {
  extern __shared__ char smem[];
  const int tid = threadIdx.x;
  const int w = tid >> 6;          // wave 0..7
  const int lane = tid & 63;
  const int g = lane >> 4;
  const int s = lane & 15;
  const int s0 = blockIdx.x * 16;

  // ---- stage x: XP[ss][t] ----
  for (int i = tid; i < 16 * 512; i += 512) {
    const int ss = i >> 9, t = i & 511;
    *(float*)(smem + XP + ss * XPITCH + t * 4) = y[(size_t)(s0 + ss) * 512 + t];
  }
  // ---- zero all 16 h planes ----
  for (int i = tid; i < 36864 / 4; i += 512) *(float*)(smem + HP + i * 4) = 0.f;
  // ---- init flags ----
  if (tid < 8) *(volatile int*)(smem + FLG + tid * 4) = -1;
  __syncthreads();  // the only barrier

  volatile int* cE = (volatile int*)(smem + FLG);
  volatile int* cO = (volatile int*)(smem + FLG + 16);
  const int bo0 = s * 144 + 16 * g, bo1 = bo0 + 64;

  if (w < 4) {
    // =================== E waves: layer 1, step k ===================
    short8 a1h[4][2], a1l[4][2];
#pragma unroll
    for (int p = 0; p < 4; ++p)
#pragma unroll
      for (int c = 0; c < 2; ++c)
        split8(Whh1 + (size_t)(p * 64 + 16 * w + s) * 64 + 32 * c + 8 * g,
               a1h[p][c], a1l[p][c]);
    float bias1c[4][4], wih1c[4][4];
#pragma unroll
    for (int p = 0; p < 4; ++p)
#pragma unroll
      for (int r = 0; r < 4; ++r) {
        const int row = p * 64 + 16 * w + 4 * g + r;
        bias1c[p][r] = bih1[row] + bhh1[row];
        wih1c[p][r] = Wih1[row];
      }
    float c1[4] = {0.f, 0.f, 0.f, 0.f};
    const int hwr0 = s * 144 + 32 * w + 8 * g;

#pragma unroll 1
    for (int k = 0; k < NT; ++k) {
      if (k >= 1) wait_min_ge(cE, k - 1);
      if (k >= 4) wait_min_ge(cO, k - 4);
      asm volatile("" ::: "memory");
      const int rp0 = PLANE(0, (k - 1) & 3, 0), rp1 = PLANE(0, (k - 1) & 3, 1);
      const short8 Bh0 = *(const short8*)(smem + rp0 + bo0);
      const short8 Bl0 = *(const short8*)(smem + rp1 + bo0);
      const short8 Bh1 = *(const short8*)(smem + rp0 + bo1);
      const short8 Bl1 = *(const short8*)(smem + rp1 + bo1);
      const float x = *(const float*)(smem + XP + s * XPITCH + k * 4);
      f32x4 acc[4], acx[4];
#pragma unroll
      for (int p = 0; p < 4; ++p) {
#pragma unroll
        for (int r = 0; r < 4; ++r) acc[p][r] = fmaf(wih1c[p][r], x, bias1c[p][r]);
        acx[p] = (f32x4){0.f, 0.f, 0.f, 0.f};
      }
      __builtin_amdgcn_s_setprio(1);
#pragma unroll
      for (int p = 0; p < 4; ++p) acc[p] = mfma16(a1h[p][0], Bh0, acc[p]);
#pragma unroll
      for (int p = 0; p < 4; ++p) acx[p] = mfma16(a1h[p][1], Bh1, acx[p]);
#pragma unroll
      for (int p = 0; p < 4; ++p) acc[p] = mfma16(a1h[p][0], Bl0, acc[p]);
#pragma unroll
      for (int p = 0; p < 4; ++p) acx[p] = mfma16(a1h[p][1], Bl1, acx[p]);
#pragma unroll
      for (int p = 0; p < 4; ++p) acc[p] = mfma16(a1l[p][0], Bh0, acc[p]);
#pragma unroll
      for (int p = 0; p < 4; ++p) acx[p] = mfma16(a1l[p][1], Bh1, acx[p]);
      __builtin_amdgcn_s_setprio(0);
#pragma unroll
      for (int p = 0; p < 4; ++p) acc[p] += acx[p];

      float h1n[4];
#pragma unroll
      for (int r = 0; r < 4; ++r)
        cell(acc[0][r], acc[1][r], acc[2][r], acc[3][r], c1[r], h1n[r]);
      const unsigned hA = cvt_pk(h1n[0], h1n[1]), hB = cvt_pk(h1n[2], h1n[3]);
      const unsigned lA = cvt_pk(h1n[0] - __uint_as_float(hA << 16),
                                 h1n[1] - __uint_as_float(hA & 0xFFFF0000u));
      const unsigned lB = cvt_pk(h1n[2] - __uint_as_float(hB << 16),
                                 h1n[3] - __uint_as_float(hB & 0xFFFF0000u));
      *(uint2*)(smem + PLANE(0, k & 3, 0) + hwr0) = make_uint2(hA, hB);
      *(uint2*)(smem + PLANE(0, k & 3, 1) + hwr0) = make_uint2(lA, lB);
      asm volatile("s_waitcnt lgkmcnt(0)" ::: "memory");
      if (lane == 0) cE[w] = k;
    }
  } else {
    // =================== O waves: layer 2, step j ===================
    const int ow = w - 4;
    short8 a2h[4][4], a2l[4][4];  // c: 0,1 = Wih2 halves; 2,3 = Whh2 halves
#pragma unroll
    for (int p = 0; p < 4; ++p)
#pragma unroll
      for (int c = 0; c < 4; ++c) {
        const float* src = (c < 2) ? (Wih2 + (size_t)(p * 64 + 16 * ow + s) * 64 + 32 * c + 8 * g)
                                   : (Whh2 + (size_t)(p * 64 + 16 * ow + s) * 64 + 32 * (c - 2) + 8 * g);
        split8(src, a2h[p][c], a2l[p][c]);
      }
    float bias2c[4][4], wlinc[4];
#pragma unroll
    for (int p = 0; p < 4; ++p)
#pragma unroll
      for (int r = 0; r < 4; ++r)
        bias2c[p][r] = bih2[p * 64 + 16 * ow + 4 * g + r] +
                       bhh2[p * 64 + 16 * ow + 4 * g + r];
#pragma unroll
    for (int r = 0; r < 4; ++r) wlinc[r] = Wlin[16 * ow + 4 * g + r];
    const float bl0 = blin[0];
    float c2[4] = {0.f, 0.f, 0.f, 0.f};
    const int hwr0 = s * 144 + 32 * ow + 8 * g;

#pragma unroll 1
    for (int j = 0; j < NT; ++j) {
      wait_min_ge(cE, j);
      if (j >= 1) wait_min_ge(cO, j - 1);
      asm volatile("" ::: "memory");

      // ---- flush 64 out columns (ring entries all complete: min cO >= j-1) ----
      if (j >= 66 && ((j - 2) & 63) == 0) {
        const int base = j - 66;
        const int thr = ow * 64 + lane;
        const int ss2 = thr & 15, grp = thr >> 4;
#pragma unroll
        for (int q = 0; q < 4; ++q) {
          const int idx = base + grp * 4 + q;
          const char* op = smem + RING + (idx & 127) * 256 + ss2 * 4;
          const float v = *(const float*)(op) + *(const float*)(op + 64) +
                          *(const float*)(op + 128) + *(const float*)(op + 192) + bl0;
          out[(size_t)(s0 + ss2) * 511 + idx] = v;
        }
      }

      const int rp0 = PLANE(0, j & 3, 0), rp1 = PLANE(0, j & 3, 1);        // h1(j)
      const int rq0 = PLANE(1, (j - 1) & 3, 0), rq1 = PLANE(1, (j - 1) & 3, 1); // h2(j-1)
      const short8 Bh0 = *(const short8*)(smem + rp0 + bo0);
      const short8 Bl0 = *(const short8*)(smem + rp1 + bo0);
      const short8 Bh1 = *(const short8*)(smem + rp0 + bo1);
      const short8 Bl1 = *(const short8*)(smem + rp1 + bo1);
      const short8 Ch0 = *(const short8*)(smem + rq0 + bo0);
      const short8 Cl0 = *(const short8*)(smem + rq1 + bo0);
      const short8 Ch1 = *(const short8*)(smem + rq0 + bo1);
      const short8 Cl1 = *(const short8*)(smem + rq1 + bo1);
      f32x4 acc[4], acx[4];
#pragma unroll
      for (int p = 0; p < 4; ++p) {
        acc[p] = (f32x4){bias2c[p][0], bias2c[p][1], bias2c[p][2], bias2c[p][3]};
        acx[p] = (f32x4){0.f, 0.f, 0.f, 0.f};
      }
      __builtin_amdgcn_s_setprio(1);
#pragma unroll
      for (int p = 0; p < 4; ++p) acc[p] = mfma16(a2h[p][0], Bh0, acc[p]);
#pragma unroll
      for (int p = 0; p < 4; ++p) acx[p] = mfma16(a2h[p][1], Bh1, acx[p]);
#pragma unroll
      for (int p = 0; p < 4; ++p) acc[p] = mfma16(a2h[p][0], Bl0, acc[p]);
#pragma unroll
      for (int p = 0; p < 4; ++p) acx[p] = mfma16(a2h[p][1], Bl1, acx[p]);
#pragma unroll
      for (int p = 0; p < 4; ++p) acc[p] = mfma16(a2l[p][0], Bh0, acc[p]);
#pragma unroll
      for (int p = 0; p < 4; ++p) acx[p] = mfma16(a2l[p][1], Bh1, acx[p]);
#pragma unroll
      for (int p = 0; p < 4; ++p) acc[p] = mfma16(a2h[p][2], Ch0, acc[p]);
#pragma unroll
      for (int p = 0; p < 4; ++p) acx[p] = mfma16(a2h[p][3], Ch1, acx[p]);
#pragma unroll
      for (int p = 0; p < 4; ++p) acc[p] = mfma16(a2h[p][2], Cl0, acc[p]);
#pragma unroll
      for (int p = 0; p < 4; ++p) acx[p] = mfma16(a2h[p][3], Cl1, acx[p]);
#pragma unroll
      for (int p = 0; p < 4; ++p) acc[p] = mfma16(a2l[p][2], Ch0, acc[p]);
#pragma unroll
      for (int p = 0; p < 4; ++p) acx[p] = mfma16(a2l[p][3], Ch1, acx[p]);
      __builtin_amdgcn_s_setprio(0);
#pragma unroll
      for (int p = 0; p < 4; ++p) acc[p] += acx[p];

      float h2n[4];
#pragma unroll
      for (int r = 0; r < 4; ++r)
        cell(acc[0][r], acc[1][r], acc[2][r], acc[3][r], c2[r], h2n[r]);
      const unsigned hA = cvt_pk(h2n[0], h2n[1]), hB = cvt_pk(h2n[2], h2n[3]);
      const unsigned lA = cvt_pk(h2n[0] - __uint_as_float(hA << 16),
                                 h2n[1] - __uint_as_float(hA & 0xFFFF0000u));
      const unsigned lB = cvt_pk(h2n[2] - __uint_as_float(hB << 16),
                                 h2n[3] - __uint_as_float(hB & 0xFFFF0000u));
      *(uint2*)(smem + PLANE(1, j & 3, 0) + hwr0) = make_uint2(hA, hB);
      *(uint2*)(smem + PLANE(1, j & 3, 1) + hwr0) = make_uint2(lA, lB);

      if (j >= 1) {  // out partial for ring idx j-1 (= out col j-1 <- h2(j)... dot of h2n)
        float pw = wlinc[0] * h2n[0];
        pw = fmaf(wlinc[1], h2n[1], pw);
        pw = fmaf(wlinc[2], h2n[2], pw);
        pw = fmaf(wlinc[3], h2n[3], pw);
        pw += __shfl_xor(pw, 16, 64);
        pw += __shfl_xor(pw, 32, 64);
        if (g == 0)
          *(float*)(smem + RING + ((j - 1) & 127) * 256 + ow * 64 + s * 4) = pw;
      }
      asm volatile("s_waitcnt lgkmcnt(0)" ::: "memory");
      if (lane == 0) cO[ow] = j;
    }

    // ---- tail: flush out cols 448..510 ----
    wait_min_ge(cO, NT - 1);
    asm volatile("" ::: "memory");
    {
      const int thr = ow * 64 + lane;
      for (int e = thr; e < 63 * 16; e += 256) {
        const int ss2 = e & 15, off = e >> 4;
        const int idx = 448 + off;
        const char* op = smem + RING + (idx & 127) * 256 + ss2 * 4;
        const float v = *(const float*)(op) + *(const float*)(op + 64) +
                        *(const float*)(op + 128) + *(const float*)(op + 192) + bl0;
        out[(size_t)(s0 + ss2) * 511 + idx] = v;
      }
    }
  }
}

extern "C" void kernel_launch(void* const* d_in, const int* in_sizes, int n_in,
                              void* d_out, int out_size, void* d_ws, size_t ws_size,
                              hipStream_t stream) {
  const float* y    = (const float*)d_in[0];
  const float* Wih1 = (const float*)d_in[1];
  const float* Whh1 = (const float*)d_in[2];
  const float* bih1 = (const float*)d_in[3];
  const float* bhh1 = (const float*)d_in[4];
  const float* Wih2 = (const float*)d_in[5];
  const float* Whh2 = (const float*)d_in[6];
  const float* bih2 = (const float*)d_in[7];
  const float* bhh2 = (const float*)d_in[8];
  const float* Wlin = (const float*)d_in[9];
  const float* blin = (const float*)d_in[10];
  float* out = (float*)d_out;

  hipFuncSetAttribute((const void*)lstm2_async,
                      hipFuncAttributeMaxDynamicSharedMemorySize, LDS_BYTES);
  lstm2_async<<<dim3(128), dim3(512), LDS_BYTES, stream>>>(
      y, Wih1, Whh1, bih1, bhh1, Wih2, Whh2, bih2, bhh2, Wlin, blin, out);
}

// Round 10
// 649.645 us; speedup vs baseline: 1.2235x; 1.2235x over previous
//
#include <hip/hip_runtime.h>

// 2-layer LSTM (H=64, D=1), N=2048, T=512 — MFMA bf16 3-term split precision.
// R10 = R6 (best, 648us) + sync/tail overhead bundle:
//  - raw s_barrier + manual lgkmcnt(0) (no vmcnt drain; flush stores fly)
//  - O's out-dot deferred to next iter's pre-phase (off the critical tail,
//    desyncs E/O phase alignment after the barrier)
//  - ring flush moved to E (lighter role), corrected schedule:
//    pos p written at iter p+3 -> in-loop flush [k-67,k-4] at k=65,129..449,
//    tail covers 446..510
//  - x prefetched one step ahead; 2-accumulator MFMA chains (from R9)
// Structure: 128 blocks x 512 threads (8 waves, 2/SIMD). E waves 0-3 = L1
// step k; O waves 4-7 = L2 step k-1. One barrier per iteration. h1/h2
// planes double-buffered by parity.

typedef __attribute__((ext_vector_type(8))) short short8;
typedef __attribute__((ext_vector_type(4))) float f32x4;

#define NT 512
#define XPITCH 2060              // 515 words (odd) -> conflict-free x reads
#define XP 0                     // 16 * 2060 = 32960
#define HP 32960                 // 8 planes * 2304 = 18432
#define RING 51392               // 128 slots * 256 B (4 ow x 16 s x f32)
#define LDS_BYTES 84160
// plane(layer 0=h1/1=h2, buf 0/1, hl): [16 s][144 B], row j at byte s*144+2j
#define PLANE(layer, buf, hl) (HP + ((((layer) * 2 + (buf)) * 2) + (hl)) * 2304)

__device__ __forceinline__ float fast_rcp(float x) { return __builtin_amdgcn_rcpf(x); }
__device__ __forceinline__ unsigned short bf_rne(float f) {
  unsigned u = __float_as_uint(f);
  return (unsigned short)((u + 0x7FFFu + ((u >> 16) & 1u)) >> 16);
}
__device__ __forceinline__ void split8(const float* p, short8& hi, short8& lo) {
#pragma unroll
  for (int e = 0; e < 8; ++e) {
    float v = p[e];
    unsigned short h = bf_rne(v);
    float hf = __uint_as_float(((unsigned)h) << 16);
    hi[e] = (short)h;
    lo[e] = (short)bf_rne(v - hf);
  }
}
__device__ __forceinline__ unsigned cvt_pk(float a, float b) {
  unsigned r;
  asm("v_cvt_pk_bf16_f32 %0, %1, %2" : "=v"(r) : "v"(a), "v"(b));
  return r;
}
__device__ __forceinline__ f32x4 mfma16(short8 a, short8 b, f32x4 c) {
  return __builtin_amdgcn_mfma_f32_16x16x32_bf16(a, b, c, 0, 0, 0);
}
// (c,h) update from 4 gate pre-activations: 5 exp + 3 rcp.
__device__ __forceinline__ void cell(float i, float f, float gg, float o,
                                     float& c, float& h) {
  const float ei = __expf(-i), ef = __expf(-f), eg = __expf(-2.f * gg),
              eo = __expf(-o);
  const float P = (1.f - eg) * fast_rcp((1.f + ei) * (1.f + eg));
  c = fmaf(c, fast_rcp(1.f + ef), P);
  const float cc = fminf(15.f, fmaxf(-15.f, c));
  const float ec = __expf(-2.f * cc);
  h = (1.f - ec) * fast_rcp((1.f + eo) * (1.f + ec));
}
// Raw barrier: only LDS drained (lgkmcnt). Global flush stores are NOT
// waited on (fly across barriers; retired before endpgm by compiler).
// sched_barrier + "memory" fences per guide rule #18.
__device__ __forceinline__ void fast_barrier() {
  __builtin_amdgcn_sched_barrier(0);
  asm volatile("s_waitcnt lgkmcnt(0)" ::: "memory");
  __builtin_amdgcn_s_barrier();
  asm volatile("" ::: "memory");
  __builtin_amdgcn_sched_barrier(0);
}

__global__ __launch_bounds__(512, 2) void lstm2_r10(
    const float* __restrict__ y, const float* __restrict__ Wih1,
    const float* __restrict__ Whh1, const float* __restrict__ bih1,
    const float* __restrict__ bhh1, const float* __restrict__ Wih2,
    const float* __restrict__ Whh2, const float* __restrict__ bih2,
    const float* __restrict__ bhh2, const float* __restrict__ Wlin,
    const float* __restrict__ blin, float* __restrict__ out) {
  extern __shared__ char smem[];
  const int tid = threadIdx.x;
  const int w = tid >> 6;          // wave 0..7
  const int lane = tid & 63;
  const int g = lane >> 4;
  const int s = lane & 15;
  const int s0 = blockIdx.x * 16;

  // ---- stage x: XP[ss][t] ----
  for (int i = tid; i < 16 * 512; i += 512) {
    const int ss = i >> 9, t = i & 511;
    *(float*)(smem + XP + ss * XPITCH + t * 4) = y[(size_t)(s0 + ss) * 512 + t];
  }
  // ---- zero all 8 h planes ----
  for (int i = tid; i < 18432 / 4; i += 512) *(float*)(smem + HP + i * 4) = 0.f;
  const float bl0 = blin[0];
  __syncthreads();  // full barrier once (drains staging)

  const int bo0 = s * 144 + 16 * g, bo1 = bo0 + 64;

  if (w < 4) {
    // =================== E waves: layer 1, step k; also ring flush ==========
    short8 a1h[4][2], a1l[4][2];
#pragma unroll
    for (int p = 0; p < 4; ++p)
#pragma unroll
      for (int c = 0; c < 2; ++c)
        split8(Whh1 + (size_t)(p * 64 + 16 * w + s) * 64 + 32 * c + 8 * g,
               a1h[p][c], a1l[p][c]);
    float bias1c[4][4], wih1c[4][4];
#pragma unroll
    for (int p = 0; p < 4; ++p)
#pragma unroll
      for (int r = 0; r < 4; ++r) {
        const int row = p * 64 + 16 * w + 4 * g + r;
        bias1c[p][r] = bih1[row] + bhh1[row];
        wih1c[p][r] = Wih1[row];
      }
    float c1[4] = {0.f, 0.f, 0.f, 0.f};
    const int hwr0 = s * 144 + 32 * w + 8 * g;
    float xnext = *(const float*)(smem + XP + s * XPITCH);

#pragma unroll 1
    for (int k = 0; k <= NT; ++k) {
      // ---- pre-phase: flush 64 ring entries [k-67, k-4] (all written; see hdr) ----
      if (k >= 65 && (k & 63) == 1) {
        const int thr = w * 64 + lane;
        const int s2 = thr >> 4, iq = thr & 15;
        const int f0 = k - 67;
        float* ob = out + (size_t)(s0 + s2) * 511;
#pragma unroll
        for (int u = 0; u < 4; ++u) {
          const int p = f0 + iq * 4 + u;
          if (p >= 0) {
            const char* op = smem + RING + (p & 127) * 256 + s2 * 4;
            ob[p] = *(const float*)(op) + *(const float*)(op + 64) +
                    *(const float*)(op + 128) + *(const float*)(op + 192) + bl0;
          }
        }
      }
      if (k < NT) {
        const float x = xnext;
        const int nk = (k + 1 < NT) ? k + 1 : NT - 1;
        xnext = *(const float*)(smem + XP + s * XPITCH + nk * 4);  // prefetch
        const int rp0 = PLANE(0, (k - 1) & 1, 0), rp1 = PLANE(0, (k - 1) & 1, 1);
        const short8 Bh0 = *(const short8*)(smem + rp0 + bo0);
        const short8 Bl0 = *(const short8*)(smem + rp1 + bo0);
        const short8 Bh1 = *(const short8*)(smem + rp0 + bo1);
        const short8 Bl1 = *(const short8*)(smem + rp1 + bo1);
        f32x4 acc[4], acx[4];
#pragma unroll
        for (int p = 0; p < 4; ++p) {
#pragma unroll
          for (int r = 0; r < 4; ++r) acc[p][r] = fmaf(wih1c[p][r], x, bias1c[p][r]);
          acx[p] = (f32x4){0.f, 0.f, 0.f, 0.f};
        }
        __builtin_amdgcn_s_setprio(1);
#pragma unroll
        for (int p = 0; p < 4; ++p) acc[p] = mfma16(a1h[p][0], Bh0, acc[p]);
#pragma unroll
        for (int p = 0; p < 4; ++p) acx[p] = mfma16(a1h[p][1], Bh1, acx[p]);
#pragma unroll
        for (int p = 0; p < 4; ++p) acc[p] = mfma16(a1h[p][0], Bl0, acc[p]);
#pragma unroll
        for (int p = 0; p < 4; ++p) acx[p] = mfma16(a1h[p][1], Bl1, acx[p]);
#pragma unroll
        for (int p = 0; p < 4; ++p) acc[p] = mfma16(a1l[p][0], Bh0, acc[p]);
#pragma unroll
        for (int p = 0; p < 4; ++p) acx[p] = mfma16(a1l[p][1], Bh1, acx[p]);
        __builtin_amdgcn_s_setprio(0);
#pragma unroll
        for (int p = 0; p < 4; ++p) acc[p] += acx[p];

        float h1n[4];
#pragma unroll
        for (int r = 0; r < 4; ++r)
          cell(acc[0][r], acc[1][r], acc[2][r], acc[3][r], c1[r], h1n[r]);
        const unsigned hA = cvt_pk(h1n[0], h1n[1]), hB = cvt_pk(h1n[2], h1n[3]);
        const unsigned lA = cvt_pk(h1n[0] - __uint_as_float(hA << 16),
                                   h1n[1] - __uint_as_float(hA & 0xFFFF0000u));
        const unsigned lB = cvt_pk(h1n[2] - __uint_as_float(hB << 16),
                                   h1n[3] - __uint_as_float(hB & 0xFFFF0000u));
        *(uint2*)(smem + PLANE(0, k & 1, 0) + hwr0) = make_uint2(hA, hB);
        *(uint2*)(smem + PLANE(0, k & 1, 1) + hwr0) = make_uint2(lA, lB);
      }
      fast_barrier();
    }
    __syncthreads();  // O's final ring write visible
    // ---- tail flush: positions 446..510 (65 entries) ----
    {
      const int thr = w * 64 + lane;
      for (int e = thr; e < 65 * 16; e += 256) {
        const int s2 = e & 15, off = e >> 4;
        const int p = 446 + off;
        const char* op = smem + RING + (p & 127) * 256 + s2 * 4;
        out[(size_t)(s0 + s2) * 511 + p] =
            *(const float*)(op) + *(const float*)(op + 64) +
            *(const float*)(op + 128) + *(const float*)(op + 192) + bl0;
      }
    }
  } else {
    // =================== O waves: layer 2, step k-1 ===================
    const int ow = w - 4;
    short8 a2h[4][4], a2l[4][4];  // c: 0,1 = Wih2 halves; 2,3 = Whh2 halves
#pragma unroll
    for (int p = 0; p < 4; ++p)
#pragma unroll
      for (int c = 0; c < 4; ++c) {
        const float* src = (c < 2) ? (Wih2 + (size_t)(p * 64 + 16 * ow + s) * 64 + 32 * c + 8 * g)
                                   : (Whh2 + (size_t)(p * 64 + 16 * ow + s) * 64 + 32 * (c - 2) + 8 * g);
        split8(src, a2h[p][c], a2l[p][c]);
      }
    float bias2c[4][4], wlinc[4];
#pragma unroll
    for (int p = 0; p < 4; ++p)
#pragma unroll
      for (int r = 0; r < 4; ++r)
        bias2c[p][r] = bih2[p * 64 + 16 * ow + 4 * g + r] +
                       bhh2[p * 64 + 16 * ow + 4 * g + r];
#pragma unroll
    for (int r = 0; r < 4; ++r) wlinc[r] = Wlin[16 * ow + 4 * g + r];
    float c2[4] = {0.f, 0.f, 0.f, 0.f};
    float h2p[4] = {0.f, 0.f, 0.f, 0.f};  // h2 computed last iteration
    const int hwr0 = s * 144 + 32 * ow + 8 * g;

#pragma unroll 1
    for (int k = 0; k <= NT; ++k) {
      // ---- pre-phase (deferred): dot of h2(k-2) -> ring pos k-3 ----
      if (k >= 3) {
        float pw = wlinc[0] * h2p[0];
        pw = fmaf(wlinc[1], h2p[1], pw);
        pw = fmaf(wlinc[2], h2p[2], pw);
        pw = fmaf(wlinc[3], h2p[3], pw);
        pw += __shfl_xor(pw, 16, 64);
        pw += __shfl_xor(pw, 32, 64);
        if (g == 0)
          *(float*)(smem + RING + ((k - 3) & 127) * 256 + ow * 64 + s * 4) = pw;
      }
      if (k >= 1) {
        const int rp0 = PLANE(0, (k - 1) & 1, 0), rp1 = PLANE(0, (k - 1) & 1, 1); // h1(k-1)
        const int rq0 = PLANE(1, k & 1, 0), rq1 = PLANE(1, k & 1, 1);             // h2(k-2)
        const short8 Bh0 = *(const short8*)(smem + rp0 + bo0);
        const short8 Bl0 = *(const short8*)(smem + rp1 + bo0);
        const short8 Bh1 = *(const short8*)(smem + rp0 + bo1);
        const short8 Bl1 = *(const short8*)(smem + rp1 + bo1);
        const short8 Ch0 = *(const short8*)(smem + rq0 + bo0);
        const short8 Cl0 = *(const short8*)(smem + rq1 + bo0);
        const short8 Ch1 = *(const short8*)(smem + rq0 + bo1);
        const short8 Cl1 = *(const short8*)(smem + rq1 + bo1);
        f32x4 acc[4], acx[4];
#pragma unroll
        for (int p = 0; p < 4; ++p) {
          acc[p] = (f32x4){bias2c[p][0], bias2c[p][1], bias2c[p][2], bias2c[p][3]};
          acx[p] = (f32x4){0.f, 0.f, 0.f, 0.f};
        }
        __builtin_amdgcn_s_setprio(1);
#pragma unroll
        for (int p = 0; p < 4; ++p) acc[p] = mfma16(a2h[p][0], Bh0, acc[p]);
#pragma unroll
        for (int p = 0; p < 4; ++p) acx[p] = mfma16(a2h[p][1], Bh1, acx[p]);
#pragma unroll
        for (int p = 0; p < 4; ++p) acc[p] = mfma16(a2h[p][0], Bl0, acc[p]);
#pragma unroll
        for (int p = 0; p < 4; ++p) acx[p] = mfma16(a2h[p][1], Bl1, acx[p]);
#pragma unroll
        for (int p = 0; p < 4; ++p) acc[p] = mfma16(a2l[p][0], Bh0, acc[p]);
#pragma unroll
        for (int p = 0; p < 4; ++p) acx[p] = mfma16(a2l[p][1], Bh1, acx[p]);
#pragma unroll
        for (int p = 0; p < 4; ++p) acc[p] = mfma16(a2h[p][2], Ch0, acc[p]);
#pragma unroll
        for (int p = 0; p < 4; ++p) acx[p] = mfma16(a2h[p][3], Ch1, acx[p]);
#pragma unroll
        for (int p = 0; p < 4; ++p) acc[p] = mfma16(a2h[p][2], Cl0, acc[p]);
#pragma unroll
        for (int p = 0; p < 4; ++p) acx[p] = mfma16(a2h[p][3], Cl1, acx[p]);
#pragma unroll
        for (int p = 0; p < 4; ++p) acc[p] = mfma16(a2l[p][2], Ch0, acc[p]);
#pragma unroll
        for (int p = 0; p < 4; ++p) acx[p] = mfma16(a2l[p][3], Ch1, acx[p]);
        __builtin_amdgcn_s_setprio(0);
#pragma unroll
        for (int p = 0; p < 4; ++p) acc[p] += acx[p];

        float h2n[4];
#pragma unroll
        for (int r = 0; r < 4; ++r)
          cell(acc[0][r], acc[1][r], acc[2][r], acc[3][r], c2[r], h2n[r]);
        const unsigned hA = cvt_pk(h2n[0], h2n[1]), hB = cvt_pk(h2n[2], h2n[3]);
        const unsigned lA = cvt_pk(h2n[0] - __uint_as_float(hA << 16),
                                   h2n[1] - __uint_as_float(hA & 0xFFFF0000u));
        const unsigned lB = cvt_pk(h2n[2] - __uint_as_float(hB << 16),
                                   h2n[3] - __uint_as_float(hB & 0xFFFF0000u));
        *(uint2*)(smem + PLANE(1, (k - 1) & 1, 0) + hwr0) = make_uint2(hA, hB);
        *(uint2*)(smem + PLANE(1, (k - 1) & 1, 1) + hwr0) = make_uint2(lA, lB);
#pragma unroll
        for (int r = 0; r < 4; ++r) h2p[r] = h2n[r];
      }
      fast_barrier();
    }
    // ---- final dot: h2(511) -> ring pos 510 ----
    {
      float pw = wlinc[0] * h2p[0];
      pw = fmaf(wlinc[1], h2p[1], pw);
      pw = fmaf(wlinc[2], h2p[2], pw);
      pw = fmaf(wlinc[3], h2p[3], pw);
      pw += __shfl_xor(pw, 16, 64);
      pw += __shfl_xor(pw, 32, 64);
      if (g == 0)
        *(float*)(smem + RING + (510 & 127) * 256 + ow * 64 + s * 4) = pw;
    }
    __syncthreads();
    // E does the tail flush.
  }
}

extern "C" void kernel_launch(void* const* d_in, const int* in_sizes, int n_in,
                              void* d_out, int out_size, void* d_ws, size_t ws_size,
                              hipStream_t stream) {
  const float* y    = (const float*)d_in[0];
  const float* Wih1 = (const float*)d_in[1];
  const float* Whh1 = (const float*)d_in[2];
  const float* bih1 = (const float*)d_in[3];
  const float* bhh1 = (const float*)d_in[4];
  const float* Wih2 = (const float*)d_in[5];
  const float* Whh2 = (const float*)d_in[6];
  const float* bih2 = (const float*)d_in[7];
  const float* bhh2 = (const float*)d_in[8];
  const float* Wlin = (const float*)d_in[9];
  const float* blin = (const float*)d_in[10];
  float* out = (float*)d_out;

  hipFuncSetAttribute((const void*)lstm2_r10,
                      hipFuncAttributeMaxDynamicSharedMemorySize, LDS_BYTES);
  lstm2_r10<<<dim3(128), dim3(512), LDS_BYTES, stream>>>(
      y, Wih1, Whh1, bih1, bhh1, Wih2, Whh2, bih2, bhh2, Wlin, blin, out);
}